// Round 3
// baseline (40.624 us; speedup 1.0000x reference)
//
#include <hip/hip_runtime.h>
#include <hip/hip_bf16.h>

#define DIN  1024
#define DOUT 1024
#define MROWS 8192   // B*S = 4*2048

#define BM 256
#define BN 128
#define BK 64
#define NKT (DIN / BK)   // 16 K-tiles

typedef __attribute__((ext_vector_type(8))) short short8;
typedef __attribute__((ext_vector_type(4))) float f32x4;

__device__ __forceinline__ ushort f2bf(float f) {
    union { float f; unsigned u; } x; x.f = f;
    unsigned u = x.u + 0x7fffu + ((x.u >> 16) & 1u);  // RNE
    return (ushort)(u >> 16);
}

// ---------- pass 1 (fused): X f32->bf16 cvt  +  Wv [K][N] -> WvT [N][K] bf16 ----------
// blocks [0,2048): X cvt (grid-stride over 2M float4)
// blocks [2048,3072): 32x32 transpose tiles of Wv
__global__ void prep_kernel(const float* __restrict__ X, ushort* __restrict__ Xb,
                            const float* __restrict__ W, ushort* __restrict__ Wt) {
    __shared__ float tile[32][33];
    const int b = blockIdx.x;
    if (b < 2048) {
        const float4* X4 = (const float4*)X;
        ushort4* O4 = (ushort4*)Xb;
        const int n4 = MROWS * DIN / 4;
        for (int idx = b * 256 + threadIdx.x; idx < n4; idx += 2048 * 256) {
            float4 v = X4[idx];
            ushort4 o;
            o.x = f2bf(v.x); o.y = f2bf(v.y); o.z = f2bf(v.z); o.w = f2bf(v.w);
            O4[idx] = o;
        }
    } else {
        const int t = b - 2048;            // 0..1023
        const int bx = (t & 31) * 32;      // n base
        const int by = (t >> 5) * 32;      // k base
        const int tx = threadIdx.x & 31;
        const int ty = threadIdx.x >> 5;   // 0..7
#pragma unroll
        for (int i = 0; i < 32; i += 8)
            tile[ty + i][tx] = W[(size_t)(by + ty + i) * DOUT + (bx + tx)];
        __syncthreads();
#pragma unroll
        for (int i = 0; i < 32; i += 8)
            Wt[(size_t)(bx + ty + i) * DIN + (by + tx)] = f2bf(tile[tx][ty + i]);
    }
}

// ---------- pass 2: C[M][N] = Xb[M][K] @ WvT[N][K]^T + bias ----------
// Triple-buffered LDS, stage 2 K-tiles ahead, ONE barrier per K-tile,
// counted vmcnt(6) (T4, never 0 in main loop), T2 source-side XOR swizzle,
// T5 setprio around the MFMA cluster, compiler-scheduled intra-tile.
__global__ __launch_bounds__(512, 2) void gemm_bias(
    const ushort* __restrict__ Xb,    // [8192][1024] bf16
    const ushort* __restrict__ Wt,    // [1024 n][1024 k] bf16
    const float* __restrict__ bias,   // [1024]
    float* __restrict__ out)          // [8192][1024] f32
{
    __shared__ ushort As[3][BM * BK];   // 3 x 32 KiB
    __shared__ ushort Bs[3][BN * BK];   // 3 x 16 KiB   (total 144 KiB -> 1 block/CU)

    const int tid  = threadIdx.x;
    const int lane = tid & 63;
    const int wid  = tid >> 6;     // 0..7
    const int wr   = wid >> 1;     // 0..3  (wave M index, 64 rows each)
    const int wc   = wid & 1;      // 0..1  (wave N index, 64 cols each)

    // XCD-aware bijective swizzle: 256 blocks = 8 XCDs x 32.
    // Each XCD: 4 m-tiles x 8 n-tiles -> A panel 2MB + full Wt 2MB = L2-fit.
    const int bid = blockIdx.x;
    const int swz = (bid & 7) * 32 + (bid >> 3);
    const int bm = (swz >> 3) * BM;
    const int bn = (swz & 7) * BN;

    // Stage half h (h=0,1) of K-tile kt into buffer b. LDS dest LINEAR;
    // T2 swizzle via XOR-permuted global source chunk (rule #21 involution).
    auto stageHalf = [&](int b, int kt, int h) {
#pragma unroll
        for (int j = 0; j < 2; ++j) {
            const int c   = j * 512 + tid;      // chunk id within half (0..1023)
            const int rl  = c >> 3;             // row within half (0..127)
            const int scc = (c & 7) ^ (rl & 7); // swizzled source column chunk
            __builtin_amdgcn_global_load_lds(
                (const __attribute__((address_space(1))) void*)(Xb + (size_t)(bm + h * 128 + rl) * DIN + kt * BK + scc * 8),
                (__attribute__((address_space(3))) void*)(&As[b][h * 8192 + (j * 512 + wid * 64) * 8]),
                16, 0, 0);
        }
        {
            const int c   = tid;                // 0..511
            const int rl  = c >> 3;             // row within half (0..63)
            const int scc = (c & 7) ^ (rl & 7);
            __builtin_amdgcn_global_load_lds(
                (const __attribute__((address_space(1))) void*)(Wt + (size_t)(bn + h * 64 + rl) * DIN + kt * BK + scc * 8),
                (__attribute__((address_space(3))) void*)(&Bs[b][h * 4096 + wid * 512]),
                16, 0, 0);
        }
    };

    f32x4 acc[4][4];
#pragma unroll
    for (int i = 0; i < 4; ++i)
#pragma unroll
        for (int j = 0; j < 4; ++j)
            acc[i][j] = (f32x4){0.f, 0.f, 0.f, 0.f};

    // One K-tile: issue stage(t+2) -> 16 ds_read_b128 -> 32 MFMA (compiler
    // interleaves via its own lgkmcnt counts) -> counted vmcnt -> barrier.
    // wait: 0 = lgkm only (tail), 2 = vmcnt(6), 1 = vmcnt(0) (drain).
    auto tileBody = [&](int buf, bool doStage, int sbuf, int skt, int wait, bool bar) {
        if (doStage) {
            stageHalf(sbuf, skt, 0);
            stageHalf(sbuf, skt, 1);
        }
        short8 af[2][4], bfr[2][4];
#pragma unroll
        for (int ks = 0; ks < 2; ++ks) {
            const int sc = ((ks * 4 + (lane >> 4)) ^ (lane & 7)) * 8;
            const int am = wr * 64 + (lane & 15);
            const int bnr = wc * 64 + (lane & 15);
#pragma unroll
            for (int i = 0; i < 4; ++i)
                af[ks][i] = *(const short8*)(&As[buf][(am + i * 16) * 64 + sc]);
#pragma unroll
            for (int j = 0; j < 4; ++j)
                bfr[ks][j] = *(const short8*)(&Bs[buf][(bnr + j * 16) * 64 + sc]);
        }
        __builtin_amdgcn_s_setprio(1);
#pragma unroll
        for (int ks = 0; ks < 2; ++ks)
#pragma unroll
            for (int i = 0; i < 4; ++i)
#pragma unroll
                for (int j = 0; j < 4; ++j)
                    acc[i][j] = __builtin_amdgcn_mfma_f32_16x16x32_bf16(af[ks][i], bfr[ks][j], acc[i][j], 0, 0, 0);
        __builtin_amdgcn_s_setprio(0);
        if (wait == 2)      asm volatile("s_waitcnt vmcnt(6) lgkmcnt(0)" ::: "memory");
        else if (wait == 1) asm volatile("s_waitcnt vmcnt(0) lgkmcnt(0)" ::: "memory");
        else                asm volatile("s_waitcnt lgkmcnt(0)" ::: "memory");
        __builtin_amdgcn_sched_barrier(0);
        if (bar) __builtin_amdgcn_s_barrier();
    };

    // ---- prologue: stage tiles 0 and 1 (12 loads/thread); wait tile 0 ----
    stageHalf(0, 0, 0);
    stageHalf(0, 0, 1);
    stageHalf(1, 1, 0);
    stageHalf(1, 1, 1);
    asm volatile("s_waitcnt vmcnt(6)" ::: "memory");   // tile 0 landed, tile 1 in flight
    __builtin_amdgcn_sched_barrier(0);
    __builtin_amdgcn_s_barrier();

    // ---- main loop: compute tile t, stage tile t+2 into buffer of t-1 ----
    for (int t = 0; t < NKT - 2; ++t)                  // t = 0..13
        tileBody(t % 3, true, (t + 2) % 3, t + 2, 2, true);
    // t = 14: nothing to stage; drain tile-15 loads
    tileBody((NKT - 2) % 3, false, 0, 0, 1, true);
    // t = 15: last tile — no wait, no barrier
    tileBody((NKT - 1) % 3, false, 0, 0, 0, false);

    // ---- epilogue: bias + store. C/D: col = lane&15, row = (lane>>4)*4 + r ----
    const int crow = bm + wr * 64 + (lane >> 4) * 4;
    const int ccol = bn + wc * 64 + (lane & 15);
#pragma unroll
    for (int j = 0; j < 4; ++j) {
        const int col = ccol + j * 16;
        const float bval = bias[col];
#pragma unroll
        for (int i = 0; i < 4; ++i) {
#pragma unroll
            for (int r = 0; r < 4; ++r)
                out[(size_t)(crow + i * 16 + r) * DOUT + col] = acc[i][j][r] + bval;
        }
    }
}

// ---------- fallback (only if workspace too small): naive f32 ----------
__global__ void gemm_naive(const float* __restrict__ X, const float* __restrict__ W,
                           const float* __restrict__ b, float* __restrict__ out) {
    int n = blockIdx.x * blockDim.x + threadIdx.x;
    int m = blockIdx.y;
    float acc = b[n];
    for (int k = 0; k < DIN; ++k)
        acc += X[(size_t)m * DIN + k] * W[(size_t)k * DOUT + n];
    out[(size_t)m * DOUT + n] = acc;
}

extern "C" void kernel_launch(void* const* d_in, const int* in_sizes, int n_in,
                              void* d_out, int out_size, void* d_ws, size_t ws_size,
                              hipStream_t stream) {
    // setup_inputs order: X, Wq, bq, Wk, bk, Wv, bv
    const float* X  = (const float*)d_in[0];
    const float* Wv = (const float*)d_in[5];
    const float* bv = (const float*)d_in[6];
    float* out = (float*)d_out;

    const size_t xb_elems = (size_t)MROWS * DIN;
    const size_t wt_elems = (size_t)DOUT * DIN;
    const size_t needed = (xb_elems + wt_elems) * sizeof(ushort);

    if (ws_size < needed) {
        dim3 g(DOUT / 256, MROWS);
        gemm_naive<<<g, 256, 0, stream>>>(X, Wv, bv, out);
        return;
    }

    ushort* Xb = (ushort*)d_ws;
    ushort* Wt = Xb + xb_elems;

    prep_kernel<<<2048 + 1024, 256, 0, stream>>>(X, Xb, Wv, Wt);
    gemm_bias<<<256, 512, 0, stream>>>(Xb, Wt, bv, out);
}